// Round 15
// baseline (733.548 us; speedup 1.0000x reference)
//
#include <hip/hip_runtime.h>
#include <hip/hip_bf16.h>
#include <math.h>

// GPT-small fwd: B=2, T=1024, D=512, H=8, HD=64, L=2, V=50257
// bf16 MFMA (16x16x32) for all matmuls, fp32 residual/LN/softmax/loss.

typedef short bf16x8 __attribute__((ext_vector_type(8)));
typedef short short8 __attribute__((ext_vector_type(8)));
typedef float f32x4 __attribute__((ext_vector_type(4)));

#define NTOK   2048
#define DMODEL 512
#define TSEQ   1024
#define NVOC   50257
#define VPAD   50304
#define NPART  786        // one LSE partial per row per 64-col panel

// ---------------------------------------------------------------- helpers
__device__ __forceinline__ float gelu_exact(float x) {
    return 0.5f * x * (1.f + erff(x * 0.70710678118654752f));
}
__device__ __forceinline__ float bf2f(short s) {
    unsigned u = ((unsigned)(unsigned short)s) << 16;
    union { unsigned u; float f; } c; c.u = u; return c.f;
}

typedef __attribute__((address_space(1))) const void global_cvoid;
typedef __attribute__((address_space(3))) void lds_void;
__device__ __forceinline__ void glds16(const void* g, void* l) {
    __builtin_amdgcn_global_load_lds((global_cvoid*)g, (lds_void*)l, 16, 0, 0);
}
__device__ __forceinline__ void rawbar() {
    asm volatile("" ::: "memory");
    __builtin_amdgcn_s_barrier();
    asm volatile("" ::: "memory");
}

// ---------------------------------------------------------------- all weight f32->bf16 conversions in ONE dispatch
__global__ __launch_bounds__(256) void conv_all(
    const float* __restrict__ attw, __hip_bfloat16* __restrict__ wAtt,
    const float* __restrict__ prjw, __hip_bfloat16* __restrict__ wPrj,
    const float* __restrict__ fcw,  __hip_bfloat16* __restrict__ wFc,
    const float* __restrict__ fc2w, __hip_bfloat16* __restrict__ wFc2,
    const float* __restrict__ tok,  __hip_bfloat16* __restrict__ tokB) {
    long bid = blockIdx.x;
    const float* in; __hip_bfloat16* out; long n4, s4, base, nb;
    if (bid < 1536)      { in = attw; out = wAtt; n4 = 393216; s4 = n4; base = 0;    nb = 1536; }
    else if (bid < 2048) { in = prjw; out = wPrj; n4 = 131072; s4 = n4; base = 1536; nb = 512;  }
    else if (bid < 4096) { in = fcw;  out = wFc;  n4 = 524288; s4 = n4; base = 2048; nb = 2048; }
    else if (bid < 6144) { in = fc2w; out = wFc2; n4 = 524288; s4 = n4; base = 4096; nb = 2048; }
    else                 { in = tok;  out = tokB; n4 = (long)VPAD * 512 / 4;
                           s4 = (long)NVOC * 512 / 4; base = 6144; nb = 4096; }
    for (long i = (bid - base) * 256 + threadIdx.x; i < n4; i += nb * 256) {
        float4 v;
        if (i < s4) v = ((const float4*)in)[i];
        else { v.x = v.y = v.z = v.w = 0.f; }
        alignas(8) __hip_bfloat16 t[4];
        t[0] = __float2bfloat16(v.x); t[1] = __float2bfloat16(v.y);
        t[2] = __float2bfloat16(v.z); t[3] = __float2bfloat16(v.w);
        *(uint2*)&out[i * 4] = *(uint2*)t;
    }
}

// ---------------------------------------------------------------- embedding
__global__ __launch_bounds__(128) void embed_k(const int* __restrict__ idx,
                                               const float* __restrict__ tok,
                                               const float* __restrict__ pos,
                                               float* __restrict__ x) {
    int row = blockIdx.x;
    int t = row & (TSEQ - 1);
    int id = idx[row];
    const float4* a = (const float4*)(tok + (long)id * DMODEL);
    const float4* p = (const float4*)(pos + (long)t * DMODEL);
    float4* o = (float4*)(x + (long)row * DMODEL);
    int i = threadIdx.x;
    float4 u = a[i], q = p[i];
    u.x += q.x; u.y += q.y; u.z += q.z; u.w += q.w;
    o[i] = u;
}

// ---------------------------------------------------------------- LayerNorm (wave per row), fp32 -> bf16
__global__ __launch_bounds__(256) void ln_rows(const float* __restrict__ x,
                                               const float* __restrict__ w,
                                               const float* __restrict__ b,
                                               __hip_bfloat16* __restrict__ out,
                                               int nrows) {
    int wv = threadIdx.x >> 6, l = threadIdx.x & 63;
    int row = blockIdx.x * 4 + wv;
    if (row >= nrows) return;
    const float4* xr = (const float4*)(x + (long)row * DMODEL);
    float4 v0 = xr[l * 2], v1 = xr[l * 2 + 1];
    float s = v0.x + v0.y + v0.z + v0.w + v1.x + v1.y + v1.z + v1.w;
    for (int o = 32; o; o >>= 1) s += __shfl_xor(s, o);
    float mu = s * (1.f / DMODEL);
    float d, q = 0.f;
    d = v0.x - mu; q += d * d; d = v0.y - mu; q += d * d;
    d = v0.z - mu; q += d * d; d = v0.w - mu; q += d * d;
    d = v1.x - mu; q += d * d; d = v1.y - mu; q += d * d;
    d = v1.z - mu; q += d * d; d = v1.w - mu; q += d * d;
    for (int o = 32; o; o >>= 1) q += __shfl_xor(q, o);
    float rs = rsqrtf(q * (1.f / DMODEL) + 1e-5f);
    const float4* wr = (const float4*)w; const float4* br = (const float4*)b;
    float4 w0 = wr[l * 2], w1 = wr[l * 2 + 1], b0 = br[l * 2], b1 = br[l * 2 + 1];
    alignas(16) __hip_bfloat16 t[8];
    t[0] = __float2bfloat16((v0.x - mu) * rs * w0.x + b0.x);
    t[1] = __float2bfloat16((v0.y - mu) * rs * w0.y + b0.y);
    t[2] = __float2bfloat16((v0.z - mu) * rs * w0.z + b0.z);
    t[3] = __float2bfloat16((v0.w - mu) * rs * w0.w + b0.w);
    t[4] = __float2bfloat16((v1.x - mu) * rs * w1.x + b1.x);
    t[5] = __float2bfloat16((v1.y - mu) * rs * w1.y + b1.y);
    t[6] = __float2bfloat16((v1.z - mu) * rs * w1.z + b1.z);
    t[7] = __float2bfloat16((v1.w - mu) * rs * w1.w + b1.w);
    *(int4*)&out[(long)row * DMODEL + l * 8] = *(int4*)t;
}

// ---------------------------------------------------------------- fused causal attention (flash-style)  [r14, verified]
__global__ __launch_bounds__(256) void attn_fused(
    const __hip_bfloat16* __restrict__ qkv,    // [2048][1536]
    __hip_bfloat16* __restrict__ y) {          // [2048][512]
    __shared__ __align__(16) __hip_bfloat16 Klds[8 * 512];
    __shared__ __align__(16) __hip_bfloat16 Vlds[64][66];
    __shared__ __align__(16) __hip_bfloat16 Plds[4][16][66];
    const int tid = threadIdx.x;
    const int l = tid & 63, w = tid >> 6;
    const int lr = l & 15, lk = l >> 4;
    const int bx = blockIdx.x, z = blockIdx.y;
    const int bb = z >> 3, h = z & 7;
    const int q0 = bx * 64;
    const long tokbase = (long)bb * TSEQ;

    bf16x8 qf[2];
#pragma unroll
    for (int ks = 0; ks < 2; ++ks)
        qf[ks] = *(const bf16x8*)&qkv[(tokbase + q0 + w * 16 + lr) * 1536 +
                                      h * 64 + ks * 32 + lk * 8];

    f32x4 oacc[4];
    float m_[4], l_[4];
#pragma unroll
    for (int n = 0; n < 4; ++n)
        for (int r = 0; r < 4; ++r) oacc[n][r] = 0.f;
#pragma unroll
    for (int r = 0; r < 4; ++r) { m_[r] = -INFINITY; l_[r] = 0.f; }

    const int vk = tid >> 2, vd0 = (tid & 3) * 16;

    for (int kt = 0; kt <= bx; ++kt) {
        const int k0 = kt * 64;
        __syncthreads();
#pragma unroll
        for (int i = 0; i < 2; ++i) {
            int c = w * 2 + i, cg = c >> 1, ds = c & 1;
            glds16(&qkv[(tokbase + k0 + cg * 16 + lr) * 1536 + 512 + h * 64 +
                        ds * 32 + lk * 8],
                   &Klds[c * 512]);
        }
        {
            const __hip_bfloat16* vg =
                &qkv[(tokbase + k0 + vk) * 1536 + 1024 + h * 64 + vd0];
            bf16x8 v0 = *(const bf16x8*)vg;
            bf16x8 v1 = *(const bf16x8*)(vg + 8);
#pragma unroll
            for (int e = 0; e < 8; ++e) {
                Vlds[vd0 + e][vk] = ((const __hip_bfloat16*)&v0)[e];
                Vlds[vd0 + 8 + e][vk] = ((const __hip_bfloat16*)&v1)[e];
            }
        }
        __syncthreads();

        f32x4 sacc[4];
#pragma unroll
        for (int n = 0; n < 4; ++n)
            for (int r = 0; r < 4; ++r) sacc[n][r] = 0.f;
#pragma unroll
        for (int ks = 0; ks < 2; ++ks) {
#pragma unroll
            for (int n = 0; n < 4; ++n) {
                bf16x8 kf = *(const bf16x8*)&Klds[(n * 2 + ks) * 512 + l * 8];
                sacc[n] = __builtin_amdgcn_mfma_f32_16x16x32_bf16(
                    qf[ks], kf, sacc[n], 0, 0, 0);
            }
        }

        const bool diag = (kt == bx);
#pragma unroll
        for (int r = 0; r < 4; ++r) {
            int rowg = q0 + w * 16 + lk * 4 + r;
            float rmax = -INFINITY;
#pragma unroll
            for (int n = 0; n < 4; ++n) {
                float sv = sacc[n][r] * 0.125f;
                if (diag && (k0 + n * 16 + lr) > rowg) sv = -INFINITY;
                rmax = fmaxf(rmax, sv);
            }
            rmax = fmaxf(rmax, __shfl_xor(rmax, 1, 16));
            rmax = fmaxf(rmax, __shfl_xor(rmax, 2, 16));
            rmax = fmaxf(rmax, __shfl_xor(rmax, 4, 16));
            rmax = fmaxf(rmax, __shfl_xor(rmax, 8, 16));
            float mnew = fmaxf(m_[r], rmax);
            float osc = __expf(m_[r] - mnew);
            float rsum = 0.f;
#pragma unroll
            for (int n = 0; n < 4; ++n) {
                float sv = sacc[n][r] * 0.125f;
                bool msk = diag && (k0 + n * 16 + lr) > rowg;
                float p = msk ? 0.f : __expf(sv - mnew);
                rsum += p;
                Plds[w][lk * 4 + r][n * 16 + lr] = __float2bfloat16(p);
            }
            rsum += __shfl_xor(rsum, 1, 16);
            rsum += __shfl_xor(rsum, 2, 16);
            rsum += __shfl_xor(rsum, 4, 16);
            rsum += __shfl_xor(rsum, 8, 16);
            l_[r] = l_[r] * osc + rsum;
            m_[r] = mnew;
#pragma unroll
            for (int n = 0; n < 4; ++n) oacc[n][r] *= osc;
        }
        asm volatile("" ::: "memory");

#pragma unroll
        for (int ks = 0; ks < 2; ++ks) {
            bf16x8 pf = *(const bf16x8*)&Plds[w][lr][ks * 32 + lk * 8];
#pragma unroll
            for (int n = 0; n < 4; ++n) {
                bf16x8 vf = *(const bf16x8*)&Vlds[n * 16 + lr][ks * 32 + lk * 8];
                oacc[n] = __builtin_amdgcn_mfma_f32_16x16x32_bf16(
                    pf, vf, oacc[n], 0, 0, 0);
            }
        }
    }

#pragma unroll
    for (int n = 0; n < 4; ++n) {
#pragma unroll
        for (int r = 0; r < 4; ++r) {
            long row = tokbase + q0 + w * 16 + lk * 4 + r;
            y[row * 512 + h * 64 + n * 16 + lr] =
                __float2bfloat16(oacc[n][r] / l_[r]);
        }
    }
}

// ---------------------------------------------------------------- head compute: MODE 0 = direct d_out (r12), MODE 1 = panel-major Ct
template<int MODE>
__global__ __launch_bounds__(512, 4) void head_stream(
    const __hip_bfloat16* __restrict__ A,      // [2048][512]
    const __hip_bfloat16* __restrict__ B,      // [VPAD][512]
    float* __restrict__ C,                     // MODE0: [2048][NVOC]; MODE1: Ct[786][2048][64]
    float2* __restrict__ lsePart) {
    __shared__ __align__(16) __hip_bfloat16 LB[64 * 512];
    const int tid = threadIdx.x;
    const int l = tid & 63, w = tid >> 6;
    const int lr = l & 15, lk = l >> 4;
    int bx;
    if (MODE == 0) {   // chunked XCD swizzle (786 = 8*98+2) for write-merge
        int orig = blockIdx.x;
        int xcd = orig & 7, pos = orig >> 3;
        bx = (xcd < 2) ? (xcd * 99 + pos) : (2 * 99 + (xcd - 2) * 98 + pos);
    } else {
        bx = blockIdx.x;   // dense per-block writes; no swizzle needed
    }
    const int n0 = bx * 64;

#pragma unroll
    for (int i = 0; i < 8; ++i) {
        int c = w * 8 + i;
        int nn = c >> 4, kk = c & 15;
        glds16(B + (long)(n0 + nn * 16 + lr) * 512 + kk * 32 + lk * 8,
               &LB[c * 512]);
    }
    __syncthreads();

    float* Cb = (MODE == 1) ? (C + (long)bx * NTOK * 64) : C;

    for (int step = 0; step < 8; ++step) {
        int row0 = step * 256 + w * 32;
        const __hip_bfloat16* ap0 = A + (long)(row0 + lr) * 512 + lk * 8;
        const __hip_bfloat16* ap1 = ap0 + 16 * 512;
        f32x4 acc[2][4];
#pragma unroll
        for (int mf = 0; mf < 2; ++mf)
#pragma unroll
            for (int n = 0; n < 4; ++n)
                for (int r = 0; r < 4; ++r) acc[mf][n][r] = 0.f;

#pragma unroll 1
        for (int h = 0; h < 2; ++h) {
            bf16x8 a0[8], a1[8];
#pragma unroll
            for (int j = 0; j < 8; ++j) {
                a0[j] = *(const bf16x8*)(ap0 + (h * 8 + j) * 32);
                a1[j] = *(const bf16x8*)(ap1 + (h * 8 + j) * 32);
            }
#pragma unroll
            for (int j = 0; j < 8; ++j) {
                int kk = h * 8 + j;
#pragma unroll
                for (int n = 0; n < 4; ++n) {
                    bf16x8 bf = *(const bf16x8*)&LB[(n * 16 + kk) * 512 + l * 8];
                    acc[0][n] = __builtin_amdgcn_mfma_f32_16x16x32_bf16(
                        a0[j], bf, acc[0][n], 0, 0, 0);
                    acc[1][n] = __builtin_amdgcn_mfma_f32_16x16x32_bf16(
                        a1[j], bf, acc[1][n], 0, 0, 0);
                }
            }
        }

#pragma unroll
        for (int mf = 0; mf < 2; ++mf) {
#pragma unroll
            for (int r = 0; r < 4; ++r) {
                int row = row0 + mf * 16 + lk * 4 + r;
                float mx = -INFINITY;
#pragma unroll
                for (int n = 0; n < 4; ++n) {
                    int col = n0 + n * 16 + lr;
                    if (col < NVOC) {
                        if (MODE == 0)
                            C[(long)row * NVOC + col] = acc[mf][n][r];
                        else
                            Cb[(long)row * 64 + n * 16 + lr] = acc[mf][n][r];
                        mx = fmaxf(mx, acc[mf][n][r]);
                    }
                }
                mx = fmaxf(mx, __shfl_xor(mx, 1, 16));
                mx = fmaxf(mx, __shfl_xor(mx, 2, 16));
                mx = fmaxf(mx, __shfl_xor(mx, 4, 16));
                mx = fmaxf(mx, __shfl_xor(mx, 8, 16));
                float s = 0.f;
#pragma unroll
                for (int n = 0; n < 4; ++n) {
                    int col = n0 + n * 16 + lr;
                    if (col < NVOC) s += __expf(acc[mf][n][r] - mx);
                }
                s += __shfl_xor(s, 1, 16); s += __shfl_xor(s, 2, 16);
                s += __shfl_xor(s, 4, 16); s += __shfl_xor(s, 8, 16);
                if (lr == 0)
                    lsePart[(long)row * NPART + bx] = make_float2(mx, s);
            }
        }
    }
}

// ---------------------------------------------------------------- transpose Ct[786][2048][64] -> C[2048][NVOC]
// block: 16 rows x 6 panels (384 cols). Reads 6 x 4KB contiguous chunks,
// writes 16 rows x 1.5KB bursts. Grid (128, 131).
__global__ __launch_bounds__(256) void transpose_head(
    const float* __restrict__ Ct, float* __restrict__ C) {
    __shared__ float T[16][390];   // 384 + 6 pad
    const int tid = threadIdx.x;
    const int rt = blockIdx.x, pg = blockIdx.y;
    const int r0 = rt * 16, p0 = pg * 6;
    // load phase: 1536 float4 (6 panels x 16 rows x 16 float4)
#pragma unroll
    for (int i = 0; i < 6; ++i) {
        int fl = i * 256 + tid;
        int p = fl >> 8, rem = fl & 255;
        int r = rem >> 4, c4 = rem & 15;
        f32x4 v = *(const f32x4*)&Ct[(((long)(p0 + p) * NTOK) + r0 + r) * 64 + c4 * 4];
        *(f32x4*)&T[r][p * 64 + c4 * 4] = v;
    }
    __syncthreads();
    // store phase: 16 rows x 96 float4 per row
#pragma unroll
    for (int j = 0; j < 6; ++j) {
        int fl = j * 256 + tid;
        int r = fl / 96, cc = (fl % 96) * 4;
        int gcol = p0 * 64 + cc;
        f32x4 v = *(const f32x4*)&T[r][cc];
        long rowb = (long)(r0 + r) * NVOC;
        if (gcol + 4 <= NVOC) {
            *(f32x4*)&C[rowb + gcol] = v;
        } else {
#pragma unroll
            for (int e = 0; e < 4; ++e)
                if (gcol + e < NVOC) C[rowb + gcol + e] = v[e];
        }
    }
}

// ---------------------------------------------------------------- GEMM: C = alpha * A(MxK) * B(NxK)^T [+bias][gelu][+resid]
template<int BM, int BN, int WM, int WN, bool OBF16, bool BIAS, bool GELUF,
         bool RESID>
__global__ __launch_bounds__(WM * WN * 64) void gemm_bt(
    const __hip_bfloat16* __restrict__ A, int lda, long sAhi, long sAlo,
    const __hip_bfloat16* __restrict__ B, int ldb, long sBhi, long sBlo,
    void* __restrict__ Cp, long ldc, long sChi, long sClo,
    const float* __restrict__ bias,
    int K, int Nc, float alpha, int zdiv) {
    constexpr int NW = WM * WN, NT = NW * 64;
    constexpr int FM = BM / (WM * 16), FN = BN / (WN * 16);
    constexpr int CAW = (BM / 16) / NW, CBW = (BN / 16) / NW;
    constexpr int NL = CAW + CBW;
    static_assert(CAW >= 1 && CBW >= 1 && (BM / 16) % NW == 0 &&
                  (BN / 16) % NW == 0, "chunk split");
    constexpr int STG = (BM + BN) * 32;
    constexpr int EPB = WM * 16 * BN * 4;
    constexpr int SMB = (2 * STG * 2 > EPB) ? 2 * STG * 2 : EPB;
    __shared__ __align__(16) char smem[SMB];
    __hip_bfloat16* st0 = (__hip_bfloat16*)smem;
    __hip_bfloat16* st1 = st0 + STG;
    const int tid = threadIdx.x;
    const int l = tid & 63, w = tid >> 6;
    const int wr = w / WN, wc = w % WN;
    int bx = blockIdx.x, by = blockIdx.y;
    const int z = blockIdx.z;
    const int zh = z / zdiv, zl = z % zdiv;
    const __hip_bfloat16* Az = A + (long)zh * sAhi + (long)zl * sAlo;
    const __hip_bfloat16* Bz = B + (long)zh * sBhi + (long)zl * sBlo;
    const long Coff = (long)zh * sChi + (long)zl * sClo;
    const int m0 = bx * BM, n0 = by * BN;
    const int lr = l & 15, lk = l >> 4;

    const __hip_bfloat16* pA[CAW];
    const __hip_bfloat16* pB[CBW];
#pragma unroll
    for (int i = 0; i < CAW; ++i)
        pA[i] = Az + (long)(m0 + (w * CAW + i) * 16 + lr) * lda + lk * 8;
#pragma unroll
    for (int i = 0; i < CBW; ++i)
        pB[i] = Bz + (long)(n0 + (w * CBW + i) * 16 + lr) * ldb + lk * 8;

    f32x4 acc[FM][FN];
#pragma unroll
    for (int m = 0; m < FM; ++m)
#pragma unroll
        for (int n = 0; n < FN; ++n)
            for (int r = 0; r < 4; ++r) acc[m][n][r] = 0.f;

    auto stage = [&](__hip_bfloat16* buf) {
#pragma unroll
        for (int i = 0; i < CAW; ++i) {
            glds16(pA[i], buf + (w * CAW + i) * 512);
            pA[i] += 32;
        }
#pragma unroll
        for (int i = 0; i < CBW; ++i) {
            glds16(pB[i], buf + BM * 32 + (w * CBW + i) * 512);
            pB[i] += 32;
        }
    };
    auto compute = [&](const __hip_bfloat16* buf) {
        const __hip_bfloat16* bA = buf;
        const __hip_bfloat16* bB = buf + BM * 32;
        bf16x8 af[FM], bv[FN];
#pragma unroll
        for (int m = 0; m < FM; ++m)
            af[m] = *(const bf16x8*)&bA[(wr * FM + m) * 512 + l * 8];
#pragma unroll
        for (int n = 0; n < FN; ++n)
            bv[n] = *(const bf16x8*)&bB[(wc * FN + n) * 512 + l * 8];
        __builtin_amdgcn_s_setprio(1);
#pragma unroll
        for (int m = 0; m < FM; ++m)
#pragma unroll
            for (int n = 0; n < FN; ++n)
                acc[m][n] = __builtin_amdgcn_mfma_f32_16x16x32_bf16(
                    af[m], bv[n], acc[m][n], 0, 0, 0);
        __builtin_amdgcn_s_setprio(0);
    };

    const int nt = K / 32;
    stage(st0);
    int t = 0;
    for (; t + 2 <= nt - 1; t += 2) {
        stage(st1);
        asm volatile("s_waitcnt vmcnt(%0)" :: "n"(NL) : "memory");
        rawbar();
        compute(st0);
        rawbar();
        stage(st0);
        asm volatile("s_waitcnt vmcnt(%0)" :: "n"(NL) : "memory");
        rawbar();
        compute(st1);
        rawbar();
    }
    if (t < nt - 1) {
        stage(st1);
        asm volatile("s_waitcnt vmcnt(%0)" :: "n"(NL) : "memory");
        rawbar();
        compute(st0);
        rawbar();
        asm volatile("s_waitcnt vmcnt(0)" ::: "memory");
        rawbar();
        compute(st1);
    } else {
        asm volatile("s_waitcnt vmcnt(0)" ::: "memory");
        rawbar();
        compute(st0);
    }

    __syncthreads();

    if constexpr (!RESID) {
        constexpr int EROW = 16 * BN;
        if constexpr (OBF16) {
            __hip_bfloat16* ep = (__hip_bfloat16*)smem;
            constexpr int VE = (WM * EROW) / (NT * 8);
#pragma unroll
            for (int mi = 0; mi < FM; ++mi) {
#pragma unroll
                for (int n = 0; n < FN; ++n) {
                    int cb = wc * FN * 16 + n * 16 + lr;
#pragma unroll
                    for (int r = 0; r < 4; ++r) {
                        float v = acc[mi][n][r] * alpha;
                        if (BIAS) v += bias[n0 + cb];
                        if (GELUF) v = gelu_exact(v);
                        ep[(wr * 16 + lk * 4 + r) * BN + cb] = __float2bfloat16(v);
                    }
                }
                __syncthreads();
#pragma unroll
                for (int i = 0; i < VE; ++i) {
                    int flat = (i * NT + tid) * 8;
                    int s = flat / EROW;
                    int rr = (flat % EROW) / BN;
                    int c = flat % BN;
                    long grow = m0 + s * FM * 16 + mi * 16 + rr;
                    *(short8*)((__hip_bfloat16*)Cp + Coff + grow * ldc + n0 + c) =
                        *(const short8*)(ep + flat);
                }
                __syncthreads();
            }
        } else {
            float* ep = (float*)smem;
            float* Cf = (float*)Cp;
            constexpr int VE = (WM * EROW) / (NT * 4);
#pragma unroll
            for (int mi = 0; mi < FM; ++mi) {
#pragma unroll
                for (int n = 0; n < FN; ++n) {
                    int cb = wc * FN * 16 + n * 16 + lr;
#pragma unroll
                    for (int r = 0; r < 4; ++r) {
                        float v = acc[mi][n][r] * alpha;
                        if (BIAS) v += bias[n0 + cb];
                        if (GELUF) v = gelu_exact(v);
                        ep[(wr * 16 + lk * 4 + r) * BN + cb] = v;
                    }
                }
                __syncthreads();
#pragma unroll
                for (int i = 0; i < VE; ++i) {
                    int flat = (i * NT + tid) * 4;
                    int s = flat / EROW;
                    int rr = (flat % EROW) / BN;
                    int c = flat % BN;
                    long grow = m0 + s * FM * 16 + mi * 16 + rr;
                    int gcol = n0 + c;
                    if (gcol + 4 <= Nc) {
                        *(float4*)(Cf + Coff + grow * ldc + gcol) =
                            *(const float4*)(ep + flat);
                    } else {
#pragma unroll
                        for (int e = 0; e < 4; ++e)
                            if (gcol + e < Nc)
                                Cf[Coff + grow * ldc + gcol + e] = ep[flat + e];
                    }
                }
                __syncthreads();
            }
        }
    } else {
#pragma unroll
        for (int m = 0; m < FM; ++m) {
            int rowb = m0 + wr * FM * 16 + m * 16 + lk * 4;
#pragma unroll
            for (int n = 0; n < FN; ++n) {
                int col = n0 + wc * FN * 16 + n * 16 + lr;
                if (col < Nc) {
#pragma unroll
                    for (int r = 0; r < 4; ++r) {
                        float v = acc[m][n][r] * alpha;
                        if (BIAS) v += bias[col];
                        if (GELUF) v = gelu_exact(v);
                        long cidx = Coff + (long)(rowb + r) * ldc + col;
                        float* Cf = (float*)Cp;
                        v += Cf[cidx];
                        Cf[cidx] = v;
                    }
                }
            }
        }
    }
}

// ---------------------------------------------------------------- merge per-row LSE partials -> nll
__global__ __launch_bounds__(256) void nll_part(const float2* __restrict__ part,
                                                const float* __restrict__ logits,
                                                const int* __restrict__ tgt,
                                                float* __restrict__ nll) {
    int row = blockIdx.x;
    const float2* p = part + (long)row * NPART;
    __shared__ float sm[4], ss[4];
    float m = -INFINITY, s = 0.f;
    for (int i = threadIdx.x; i < NPART; i += 256) {
        float2 v = p[i];
        float M = fmaxf(m, v.x);
        s = s * __expf(m - M) + v.y * __expf(v.x - M);
        m = M;
    }
    for (int o = 32; o; o >>= 1) {
        float om = __shfl_xor(m, o), os = __shfl_xor(s, o);
        float M = fmaxf(m, om);
        float e1 = (m == -INFINITY) ? 0.f : __expf(m - M);
        float e2 = (om == -INFINITY) ? 0.f : __expf(om - M);
        s = s * e1 + os * e2; m = M;
    }
    if ((threadIdx.x & 63) == 0) { sm[threadIdx.x >> 6] = m; ss[threadIdx.x >> 6] = s; }
    __syncthreads();
    if (threadIdx.x == 0) {
        float M = fmaxf(fmaxf(sm[0], sm[1]), fmaxf(sm[2], sm[3]));
        float S = ss[0] * expf(sm[0] - M) + ss[1] * expf(sm[1] - M) +
                  ss[2] * expf(sm[2] - M) + ss[3] * expf(sm[3] - M);
        nll[row] = M + logf(S) - logits[(long)row * NVOC + tgt[row]];
    }
}

__global__ __launch_bounds__(256) void loss_final(const float* __restrict__ nll,
                                                  float* __restrict__ out) {
    __shared__ float red[4];
    float s = 0.f;
    for (int i = threadIdx.x; i < NTOK; i += 256) s += nll[i];
    for (int o = 32; o; o >>= 1) s += __shfl_xor(s, o);
    if ((threadIdx.x & 63) == 0) red[threadIdx.x >> 6] = s;
    __syncthreads();
    if (threadIdx.x == 0)
        out[0] = (red[0] + red[1] + red[2] + red[3]) * (1.f / NTOK);
}

// ---------------------------------------------------------------- launch
extern "C" void kernel_launch(void* const* d_in, const int* in_sizes, int n_in,
                              void* d_out, int out_size, void* d_ws, size_t ws_size,
                              hipStream_t stream) {
    (void)in_sizes; (void)n_in; (void)out_size;
    const int*   idx  = (const int*)d_in[0];
    const int*   tgt  = (const int*)d_in[1];
    const float* tok  = (const float*)d_in[2];
    const float* pos  = (const float*)d_in[3];
    const float* ln1w = (const float*)d_in[4];
    const float* ln1b = (const float*)d_in[5];
    const float* attw = (const float*)d_in[6];
    const float* attb = (const float*)d_in[7];
    const float* prjw = (const float*)d_in[8];
    const float* prjb = (const float*)d_in[9];
    const float* ln2w = (const float*)d_in[10];
    const float* ln2b = (const float*)d_in[11];
    const float* fcw  = (const float*)d_in[12];
    const float* fcb  = (const float*)d_in[13];
    const float* fc2w = (const float*)d_in[14];
    const float* fc2b = (const float*)d_in[15];
    const float* lnfw = (const float*)d_in[16];
    const float* lnfb = (const float*)d_in[17];
    float* dof = (float*)d_out;

    char* base = (char*)d_ws;
    long off = 0;
    float* xf = (float*)(base + off);           off += (long)NTOK * DMODEL * 4;
    __hip_bfloat16* hbf  = (__hip_bfloat16*)(base + off); off += (long)NTOK * DMODEL * 2;
    __hip_bfloat16* qkvb = (__hip_bfloat16*)(base + off); off += (long)NTOK * 1536 * 2;
    __hip_bfloat16* Pb   = (__hip_bfloat16*)(base + off); off += 16L * TSEQ * TSEQ * 2;
    __hip_bfloat16* ybf  = (__hip_bfloat16*)(base + off); off += (long)NTOK * DMODEL * 2;
    __hip_bfloat16* fc1b = (__hip_bfloat16*)(base + off); off += (long)NTOK * 2048 * 2;
    __hip_bfloat16* wAtt = (__hip_bfloat16*)(base + off); off += 2L * 1536 * 512 * 2;
    __hip_bfloat16* wPrj = (__hip_bfloat16*)(base + off); off += 2L * 512 * 512 * 2;
    __hip_bfloat16* wFc  = (__hip_bfloat16*)(base + off); off += 2L * 2048 * 512 * 2;
    __hip_bfloat16* wFc2 = (__hip_bfloat16*)(base + off); off += 2L * 512 * 2048 * 2;
    __hip_bfloat16* tokB = (__hip_bfloat16*)(base + off); off += (long)VPAD * DMODEL * 2;
    float* nllb = (float*)(base + off);         off += NTOK * 4;
    float2* lseP = (float2*)Pb;   // aliases Pb (unused by fused attention path)
    // optional panel-major logits temp (412 MB); fall back to direct if ws small
    long ctBytes = (long)NPART * NTOK * 64 * 4;
    float* Ct = (float*)(base + off);
    bool twoPass = ((size_t)(off + ctBytes) <= ws_size);
    if ((size_t)off > ws_size) return;

    conv_all<<<dim3(10240), 256, 0, stream>>>(attw, wAtt, prjw, wPrj,
                                              fcw, wFc, fc2w, wFc2, tok, tokB);

    embed_k<<<dim3(NTOK), 128, 0, stream>>>(idx, tok, pos, xf);

    for (int l = 0; l < 2; ++l) {
        ln_rows<<<dim3(512), 256, 0, stream>>>(xf, ln1w + l * 512, ln1b + l * 512, hbf, NTOK);
        gemm_bt<128, 64, 2, 2, true, true, false, false>
            <<<dim3(16, 24, 1), 256, 0, stream>>>(
            hbf, 512, 0, 0, wAtt + (long)l * 1536 * 512, 512, 0, 0,
            qkvb, 1536, 0, 0, attb + l * 1536, 512, 1536, 1.f, 1);
        attn_fused<<<dim3(16, 16), 256, 0, stream>>>(qkvb, ybf);
        gemm_bt<64, 64, 2, 2, false, true, false, true>
            <<<dim3(32, 8, 1), 256, 0, stream>>>(
            ybf, 512, 0, 0, wPrj + (long)l * 512 * 512, 512, 0, 0,
            xf, 512, 0, 0, prjb + l * 512, 512, 512, 1.f, 1);
        ln_rows<<<dim3(512), 256, 0, stream>>>(xf, ln2w + l * 512, ln2b + l * 512, hbf, NTOK);
        gemm_bt<128, 128, 2, 2, true, true, true, false>
            <<<dim3(16, 16, 1), 256, 0, stream>>>(
            hbf, 512, 0, 0, wFc + (long)l * 2048 * 512, 512, 0, 0,
            fc1b, 2048, 0, 0, fcb + l * 2048, 512, 2048, 1.f, 1);
        gemm_bt<64, 64, 2, 2, false, true, false, true>
            <<<dim3(32, 8, 1), 256, 0, stream>>>(
            fc1b, 2048, 0, 0, wFc2 + (long)l * 512 * 2048, 2048, 0, 0,
            xf, 512, 0, 0, fc2b + l * 512, 2048, 512, 1.f, 1);
    }

    ln_rows<<<dim3(512), 256, 0, stream>>>(xf, lnfw, lnfb, hbf, NTOK);

    if (twoPass) {
        // pass 1: dense panel-major writes; pass 2: tiled transpose to d_out
        head_stream<1><<<dim3(786), 512, 0, stream>>>(hbf, tokB, Ct, lseP);
        transpose_head<<<dim3(128, 131), 256, 0, stream>>>(Ct, dof);
    } else {
        head_stream<0><<<dim3(786), 512, 0, stream>>>(hbf, tokB, dof, lseP);
    }

    nll_part<<<dim3(NTOK), 256, 0, stream>>>(lseP, dof, tgt, nllb);
    loss_final<<<dim3(1), 256, 0, stream>>>(nllb, dof + (long)NTOK * NVOC);
}

// Round 16
// 586.554 us; speedup vs baseline: 1.2506x; 1.2506x over previous
//
#include <hip/hip_runtime.h>
#include <hip/hip_bf16.h>
#include <math.h>

// GPT-small fwd: B=2, T=1024, D=512, H=8, HD=64, L=2, V=50257
// bf16 MFMA (16x16x32) for all matmuls, fp32 residual/LN/softmax/loss.
// Final configuration (r14-best): fused flash attention, r6-template layer
// GEMMs, direct streaming head with chunked-XCD swizzle (empirical floor).

typedef short bf16x8 __attribute__((ext_vector_type(8)));
typedef short short8 __attribute__((ext_vector_type(8)));
typedef float f32x4 __attribute__((ext_vector_type(4)));

#define NTOK   2048
#define DMODEL 512
#define TSEQ   1024
#define NVOC   50257
#define VPAD   50304
#define NPART  786        // one LSE partial per row per 64-col panel

// ---------------------------------------------------------------- helpers
__device__ __forceinline__ float gelu_exact(float x) {
    return 0.5f * x * (1.f + erff(x * 0.70710678118654752f));
}
__device__ __forceinline__ float bf2f(short s) {
    unsigned u = ((unsigned)(unsigned short)s) << 16;
    union { unsigned u; float f; } c; c.u = u; return c.f;
}

typedef __attribute__((address_space(1))) const void global_cvoid;
typedef __attribute__((address_space(3))) void lds_void;
__device__ __forceinline__ void glds16(const void* g, void* l) {
    __builtin_amdgcn_global_load_lds((global_cvoid*)g, (lds_void*)l, 16, 0, 0);
}
__device__ __forceinline__ void rawbar() {
    asm volatile("" ::: "memory");
    __builtin_amdgcn_s_barrier();
    asm volatile("" ::: "memory");
}

// ---------------------------------------------------------------- all weight f32->bf16 conversions in ONE dispatch
__global__ __launch_bounds__(256) void conv_all(
    const float* __restrict__ attw, __hip_bfloat16* __restrict__ wAtt,
    const float* __restrict__ prjw, __hip_bfloat16* __restrict__ wPrj,
    const float* __restrict__ fcw,  __hip_bfloat16* __restrict__ wFc,
    const float* __restrict__ fc2w, __hip_bfloat16* __restrict__ wFc2,
    const float* __restrict__ tok,  __hip_bfloat16* __restrict__ tokB) {
    long bid = blockIdx.x;
    const float* in; __hip_bfloat16* out; long n4, s4, base, nb;
    if (bid < 1536)      { in = attw; out = wAtt; n4 = 393216; s4 = n4; base = 0;    nb = 1536; }
    else if (bid < 2048) { in = prjw; out = wPrj; n4 = 131072; s4 = n4; base = 1536; nb = 512;  }
    else if (bid < 4096) { in = fcw;  out = wFc;  n4 = 524288; s4 = n4; base = 2048; nb = 2048; }
    else if (bid < 6144) { in = fc2w; out = wFc2; n4 = 524288; s4 = n4; base = 4096; nb = 2048; }
    else                 { in = tok;  out = tokB; n4 = (long)VPAD * 512 / 4;
                           s4 = (long)NVOC * 512 / 4; base = 6144; nb = 4096; }
    for (long i = (bid - base) * 256 + threadIdx.x; i < n4; i += nb * 256) {
        float4 v;
        if (i < s4) v = ((const float4*)in)[i];
        else { v.x = v.y = v.z = v.w = 0.f; }
        alignas(8) __hip_bfloat16 t[4];
        t[0] = __float2bfloat16(v.x); t[1] = __float2bfloat16(v.y);
        t[2] = __float2bfloat16(v.z); t[3] = __float2bfloat16(v.w);
        *(uint2*)&out[i * 4] = *(uint2*)t;
    }
}

// ---------------------------------------------------------------- embedding
__global__ __launch_bounds__(128) void embed_k(const int* __restrict__ idx,
                                               const float* __restrict__ tok,
                                               const float* __restrict__ pos,
                                               float* __restrict__ x) {
    int row = blockIdx.x;
    int t = row & (TSEQ - 1);
    int id = idx[row];
    const float4* a = (const float4*)(tok + (long)id * DMODEL);
    const float4* p = (const float4*)(pos + (long)t * DMODEL);
    float4* o = (float4*)(x + (long)row * DMODEL);
    int i = threadIdx.x;
    float4 u = a[i], q = p[i];
    u.x += q.x; u.y += q.y; u.z += q.z; u.w += q.w;
    o[i] = u;
}

// ---------------------------------------------------------------- LayerNorm (wave per row), fp32 -> bf16
__global__ __launch_bounds__(256) void ln_rows(const float* __restrict__ x,
                                               const float* __restrict__ w,
                                               const float* __restrict__ b,
                                               __hip_bfloat16* __restrict__ out,
                                               int nrows) {
    int wv = threadIdx.x >> 6, l = threadIdx.x & 63;
    int row = blockIdx.x * 4 + wv;
    if (row >= nrows) return;
    const float4* xr = (const float4*)(x + (long)row * DMODEL);
    float4 v0 = xr[l * 2], v1 = xr[l * 2 + 1];
    float s = v0.x + v0.y + v0.z + v0.w + v1.x + v1.y + v1.z + v1.w;
    for (int o = 32; o; o >>= 1) s += __shfl_xor(s, o);
    float mu = s * (1.f / DMODEL);
    float d, q = 0.f;
    d = v0.x - mu; q += d * d; d = v0.y - mu; q += d * d;
    d = v0.z - mu; q += d * d; d = v0.w - mu; q += d * d;
    d = v1.x - mu; q += d * d; d = v1.y - mu; q += d * d;
    d = v1.z - mu; q += d * d; d = v1.w - mu; q += d * d;
    for (int o = 32; o; o >>= 1) q += __shfl_xor(q, o);
    float rs = rsqrtf(q * (1.f / DMODEL) + 1e-5f);
    const float4* wr = (const float4*)w; const float4* br = (const float4*)b;
    float4 w0 = wr[l * 2], w1 = wr[l * 2 + 1], b0 = br[l * 2], b1 = br[l * 2 + 1];
    alignas(16) __hip_bfloat16 t[8];
    t[0] = __float2bfloat16((v0.x - mu) * rs * w0.x + b0.x);
    t[1] = __float2bfloat16((v0.y - mu) * rs * w0.y + b0.y);
    t[2] = __float2bfloat16((v0.z - mu) * rs * w0.z + b0.z);
    t[3] = __float2bfloat16((v0.w - mu) * rs * w0.w + b0.w);
    t[4] = __float2bfloat16((v1.x - mu) * rs * w1.x + b1.x);
    t[5] = __float2bfloat16((v1.y - mu) * rs * w1.y + b1.y);
    t[6] = __float2bfloat16((v1.z - mu) * rs * w1.z + b1.z);
    t[7] = __float2bfloat16((v1.w - mu) * rs * w1.w + b1.w);
    *(int4*)&out[(long)row * DMODEL + l * 8] = *(int4*)t;
}

// ---------------------------------------------------------------- fused causal attention (flash-style)  [r14, verified]
__global__ __launch_bounds__(256) void attn_fused(
    const __hip_bfloat16* __restrict__ qkv,    // [2048][1536]
    __hip_bfloat16* __restrict__ y) {          // [2048][512]
    __shared__ __align__(16) __hip_bfloat16 Klds[8 * 512];
    __shared__ __align__(16) __hip_bfloat16 Vlds[64][66];
    __shared__ __align__(16) __hip_bfloat16 Plds[4][16][66];
    const int tid = threadIdx.x;
    const int l = tid & 63, w = tid >> 6;
    const int lr = l & 15, lk = l >> 4;
    const int bx = blockIdx.x, z = blockIdx.y;
    const int bb = z >> 3, h = z & 7;
    const int q0 = bx * 64;
    const long tokbase = (long)bb * TSEQ;

    bf16x8 qf[2];
#pragma unroll
    for (int ks = 0; ks < 2; ++ks)
        qf[ks] = *(const bf16x8*)&qkv[(tokbase + q0 + w * 16 + lr) * 1536 +
                                      h * 64 + ks * 32 + lk * 8];

    f32x4 oacc[4];
    float m_[4], l_[4];
#pragma unroll
    for (int n = 0; n < 4; ++n)
        for (int r = 0; r < 4; ++r) oacc[n][r] = 0.f;
#pragma unroll
    for (int r = 0; r < 4; ++r) { m_[r] = -INFINITY; l_[r] = 0.f; }

    const int vk = tid >> 2, vd0 = (tid & 3) * 16;

    for (int kt = 0; kt <= bx; ++kt) {
        const int k0 = kt * 64;
        __syncthreads();
#pragma unroll
        for (int i = 0; i < 2; ++i) {
            int c = w * 2 + i, cg = c >> 1, ds = c & 1;
            glds16(&qkv[(tokbase + k0 + cg * 16 + lr) * 1536 + 512 + h * 64 +
                        ds * 32 + lk * 8],
                   &Klds[c * 512]);
        }
        {
            const __hip_bfloat16* vg =
                &qkv[(tokbase + k0 + vk) * 1536 + 1024 + h * 64 + vd0];
            bf16x8 v0 = *(const bf16x8*)vg;
            bf16x8 v1 = *(const bf16x8*)(vg + 8);
#pragma unroll
            for (int e = 0; e < 8; ++e) {
                Vlds[vd0 + e][vk] = ((const __hip_bfloat16*)&v0)[e];
                Vlds[vd0 + 8 + e][vk] = ((const __hip_bfloat16*)&v1)[e];
            }
        }
        __syncthreads();

        f32x4 sacc[4];
#pragma unroll
        for (int n = 0; n < 4; ++n)
            for (int r = 0; r < 4; ++r) sacc[n][r] = 0.f;
#pragma unroll
        for (int ks = 0; ks < 2; ++ks) {
#pragma unroll
            for (int n = 0; n < 4; ++n) {
                bf16x8 kf = *(const bf16x8*)&Klds[(n * 2 + ks) * 512 + l * 8];
                sacc[n] = __builtin_amdgcn_mfma_f32_16x16x32_bf16(
                    qf[ks], kf, sacc[n], 0, 0, 0);
            }
        }

        const bool diag = (kt == bx);
#pragma unroll
        for (int r = 0; r < 4; ++r) {
            int rowg = q0 + w * 16 + lk * 4 + r;
            float rmax = -INFINITY;
#pragma unroll
            for (int n = 0; n < 4; ++n) {
                float sv = sacc[n][r] * 0.125f;
                if (diag && (k0 + n * 16 + lr) > rowg) sv = -INFINITY;
                rmax = fmaxf(rmax, sv);
            }
            rmax = fmaxf(rmax, __shfl_xor(rmax, 1, 16));
            rmax = fmaxf(rmax, __shfl_xor(rmax, 2, 16));
            rmax = fmaxf(rmax, __shfl_xor(rmax, 4, 16));
            rmax = fmaxf(rmax, __shfl_xor(rmax, 8, 16));
            float mnew = fmaxf(m_[r], rmax);
            float osc = __expf(m_[r] - mnew);
            float rsum = 0.f;
#pragma unroll
            for (int n = 0; n < 4; ++n) {
                float sv = sacc[n][r] * 0.125f;
                bool msk = diag && (k0 + n * 16 + lr) > rowg;
                float p = msk ? 0.f : __expf(sv - mnew);
                rsum += p;
                Plds[w][lk * 4 + r][n * 16 + lr] = __float2bfloat16(p);
            }
            rsum += __shfl_xor(rsum, 1, 16);
            rsum += __shfl_xor(rsum, 2, 16);
            rsum += __shfl_xor(rsum, 4, 16);
            rsum += __shfl_xor(rsum, 8, 16);
            l_[r] = l_[r] * osc + rsum;
            m_[r] = mnew;
#pragma unroll
            for (int n = 0; n < 4; ++n) oacc[n][r] *= osc;
        }
        asm volatile("" ::: "memory");

#pragma unroll
        for (int ks = 0; ks < 2; ++ks) {
            bf16x8 pf = *(const bf16x8*)&Plds[w][lr][ks * 32 + lk * 8];
#pragma unroll
            for (int n = 0; n < 4; ++n) {
                bf16x8 vf = *(const bf16x8*)&Vlds[n * 16 + lr][ks * 32 + lk * 8];
                oacc[n] = __builtin_amdgcn_mfma_f32_16x16x32_bf16(
                    pf, vf, oacc[n], 0, 0, 0);
            }
        }
    }

#pragma unroll
    for (int n = 0; n < 4; ++n) {
#pragma unroll
        for (int r = 0; r < 4; ++r) {
            long row = tokbase + q0 + w * 16 + lk * 4 + r;
            y[row * 512 + h * 64 + n * 16 + lr] =
                __float2bfloat16(oacc[n][r] / l_[r]);
        }
    }
}

// ---------------------------------------------------------------- head (streaming, direct d_out):
// C[2048 x 50257] = A[2048x512] * B[VPADx512]^T + per-row-panel LSE.
// One block per 64-col panel (786 blocks, chunked-XCD-swizzled so adjacent
// panels share an XCD L2 -> boundary cache lines merge before writeback).
// B panel (64KB) staged once; each wave walks 8 steps of 32 rows.
// Empirical floor ~313us: six structural variants (dbuf, counted-vmcnt,
// phase-interleave, NT stores, transpose epilogues, dense two-pass) all
// within +-5% or worse; no pipe >30% utilized.
__global__ __launch_bounds__(512, 4) void head_stream(
    const __hip_bfloat16* __restrict__ A,      // [2048][512]
    const __hip_bfloat16* __restrict__ B,      // [VPAD][512]
    float* __restrict__ C,                     // [2048][NVOC]
    float2* __restrict__ lsePart) {
    __shared__ __align__(16) __hip_bfloat16 LB[64 * 512];   // 64KB
    const int tid = threadIdx.x;
    const int l = tid & 63, w = tid >> 6;
    const int lr = l & 15, lk = l >> 4;
    // bijective chunked XCD swizzle for 786 = 8*98 + 2 (m204 formula)
    int orig = blockIdx.x;
    int xcd = orig & 7, pos = orig >> 3;
    int bx = (xcd < 2) ? (xcd * 99 + pos) : (2 * 99 + (xcd - 2) * 98 + pos);
    const int n0 = bx * 64;

#pragma unroll
    for (int i = 0; i < 8; ++i) {
        int c = w * 8 + i;
        int nn = c >> 4, kk = c & 15;
        glds16(B + (long)(n0 + nn * 16 + lr) * 512 + kk * 32 + lk * 8,
               &LB[c * 512]);
    }
    __syncthreads();

    for (int step = 0; step < 8; ++step) {
        int row0 = step * 256 + w * 32;
        const __hip_bfloat16* ap0 = A + (long)(row0 + lr) * 512 + lk * 8;
        const __hip_bfloat16* ap1 = ap0 + 16 * 512;
        f32x4 acc[2][4];
#pragma unroll
        for (int mf = 0; mf < 2; ++mf)
#pragma unroll
            for (int n = 0; n < 4; ++n)
                for (int r = 0; r < 4; ++r) acc[mf][n][r] = 0.f;

#pragma unroll 1
        for (int h = 0; h < 2; ++h) {
            bf16x8 a0[8], a1[8];
#pragma unroll
            for (int j = 0; j < 8; ++j) {
                a0[j] = *(const bf16x8*)(ap0 + (h * 8 + j) * 32);
                a1[j] = *(const bf16x8*)(ap1 + (h * 8 + j) * 32);
            }
#pragma unroll
            for (int j = 0; j < 8; ++j) {
                int kk = h * 8 + j;
#pragma unroll
                for (int n = 0; n < 4; ++n) {
                    bf16x8 bf = *(const bf16x8*)&LB[(n * 16 + kk) * 512 + l * 8];
                    acc[0][n] = __builtin_amdgcn_mfma_f32_16x16x32_bf16(
                        a0[j], bf, acc[0][n], 0, 0, 0);
                    acc[1][n] = __builtin_amdgcn_mfma_f32_16x16x32_bf16(
                        a1[j], bf, acc[1][n], 0, 0, 0);
                }
            }
        }

#pragma unroll
        for (int mf = 0; mf < 2; ++mf) {
#pragma unroll
            for (int r = 0; r < 4; ++r) {
                int row = row0 + mf * 16 + lk * 4 + r;
                float mx = -INFINITY;
#pragma unroll
                for (int n = 0; n < 4; ++n) {
                    int col = n0 + n * 16 + lr;
                    if (col < NVOC) {
                        C[(long)row * NVOC + col] = acc[mf][n][r];
                        mx = fmaxf(mx, acc[mf][n][r]);
                    }
                }
                mx = fmaxf(mx, __shfl_xor(mx, 1, 16));
                mx = fmaxf(mx, __shfl_xor(mx, 2, 16));
                mx = fmaxf(mx, __shfl_xor(mx, 4, 16));
                mx = fmaxf(mx, __shfl_xor(mx, 8, 16));
                float s = 0.f;
#pragma unroll
                for (int n = 0; n < 4; ++n) {
                    int col = n0 + n * 16 + lr;
                    if (col < NVOC) s += __expf(acc[mf][n][r] - mx);
                }
                s += __shfl_xor(s, 1, 16); s += __shfl_xor(s, 2, 16);
                s += __shfl_xor(s, 4, 16); s += __shfl_xor(s, 8, 16);
                if (lr == 0)
                    lsePart[(long)row * NPART + bx] = make_float2(mx, s);
            }
        }
    }
}

// ---------------------------------------------------------------- GEMM: C = alpha * A(MxK) * B(NxK)^T [+bias][gelu][+resid]
template<int BM, int BN, int WM, int WN, bool OBF16, bool BIAS, bool GELUF,
         bool RESID>
__global__ __launch_bounds__(WM * WN * 64) void gemm_bt(
    const __hip_bfloat16* __restrict__ A, int lda, long sAhi, long sAlo,
    const __hip_bfloat16* __restrict__ B, int ldb, long sBhi, long sBlo,
    void* __restrict__ Cp, long ldc, long sChi, long sClo,
    const float* __restrict__ bias,
    int K, int Nc, float alpha, int zdiv) {
    constexpr int NW = WM * WN, NT = NW * 64;
    constexpr int FM = BM / (WM * 16), FN = BN / (WN * 16);
    constexpr int CAW = (BM / 16) / NW, CBW = (BN / 16) / NW;
    constexpr int NL = CAW + CBW;
    static_assert(CAW >= 1 && CBW >= 1 && (BM / 16) % NW == 0 &&
                  (BN / 16) % NW == 0, "chunk split");
    constexpr int STG = (BM + BN) * 32;
    constexpr int EPB = WM * 16 * BN * 4;
    constexpr int SMB = (2 * STG * 2 > EPB) ? 2 * STG * 2 : EPB;
    __shared__ __align__(16) char smem[SMB];
    __hip_bfloat16* st0 = (__hip_bfloat16*)smem;
    __hip_bfloat16* st1 = st0 + STG;
    const int tid = threadIdx.x;
    const int l = tid & 63, w = tid >> 6;
    const int wr = w / WN, wc = w % WN;
    int bx = blockIdx.x, by = blockIdx.y;
    const int z = blockIdx.z;
    const int zh = z / zdiv, zl = z % zdiv;
    const __hip_bfloat16* Az = A + (long)zh * sAhi + (long)zl * sAlo;
    const __hip_bfloat16* Bz = B + (long)zh * sBhi + (long)zl * sBlo;
    const long Coff = (long)zh * sChi + (long)zl * sClo;
    const int m0 = bx * BM, n0 = by * BN;
    const int lr = l & 15, lk = l >> 4;

    const __hip_bfloat16* pA[CAW];
    const __hip_bfloat16* pB[CBW];
#pragma unroll
    for (int i = 0; i < CAW; ++i)
        pA[i] = Az + (long)(m0 + (w * CAW + i) * 16 + lr) * lda + lk * 8;
#pragma unroll
    for (int i = 0; i < CBW; ++i)
        pB[i] = Bz + (long)(n0 + (w * CBW + i) * 16 + lr) * ldb + lk * 8;

    f32x4 acc[FM][FN];
#pragma unroll
    for (int m = 0; m < FM; ++m)
#pragma unroll
        for (int n = 0; n < FN; ++n)
            for (int r = 0; r < 4; ++r) acc[m][n][r] = 0.f;

    auto stage = [&](__hip_bfloat16* buf) {
#pragma unroll
        for (int i = 0; i < CAW; ++i) {
            glds16(pA[i], buf + (w * CAW + i) * 512);
            pA[i] += 32;
        }
#pragma unroll
        for (int i = 0; i < CBW; ++i) {
            glds16(pB[i], buf + BM * 32 + (w * CBW + i) * 512);
            pB[i] += 32;
        }
    };
    auto compute = [&](const __hip_bfloat16* buf) {
        const __hip_bfloat16* bA = buf;
        const __hip_bfloat16* bB = buf + BM * 32;
        bf16x8 af[FM], bv[FN];
#pragma unroll
        for (int m = 0; m < FM; ++m)
            af[m] = *(const bf16x8*)&bA[(wr * FM + m) * 512 + l * 8];
#pragma unroll
        for (int n = 0; n < FN; ++n)
            bv[n] = *(const bf16x8*)&bB[(wc * FN + n) * 512 + l * 8];
        __builtin_amdgcn_s_setprio(1);
#pragma unroll
        for (int m = 0; m < FM; ++m)
#pragma unroll
            for (int n = 0; n < FN; ++n)
                acc[m][n] = __builtin_amdgcn_mfma_f32_16x16x32_bf16(
                    af[m], bv[n], acc[m][n], 0, 0, 0);
        __builtin_amdgcn_s_setprio(0);
    };

    const int nt = K / 32;
    stage(st0);
    int t = 0;
    for (; t + 2 <= nt - 1; t += 2) {
        stage(st1);
        asm volatile("s_waitcnt vmcnt(%0)" :: "n"(NL) : "memory");
        rawbar();
        compute(st0);
        rawbar();
        stage(st0);
        asm volatile("s_waitcnt vmcnt(%0)" :: "n"(NL) : "memory");
        rawbar();
        compute(st1);
        rawbar();
    }
    if (t < nt - 1) {
        stage(st1);
        asm volatile("s_waitcnt vmcnt(%0)" :: "n"(NL) : "memory");
        rawbar();
        compute(st0);
        rawbar();
        asm volatile("s_waitcnt vmcnt(0)" ::: "memory");
        rawbar();
        compute(st1);
    } else {
        asm volatile("s_waitcnt vmcnt(0)" ::: "memory");
        rawbar();
        compute(st0);
    }

    __syncthreads();

    if constexpr (!RESID) {
        constexpr int EROW = 16 * BN;
        if constexpr (OBF16) {
            __hip_bfloat16* ep = (__hip_bfloat16*)smem;
            constexpr int VE = (WM * EROW) / (NT * 8);
#pragma unroll
            for (int mi = 0; mi < FM; ++mi) {
#pragma unroll
                for (int n = 0; n < FN; ++n) {
                    int cb = wc * FN * 16 + n * 16 + lr;
#pragma unroll
                    for (int r = 0; r < 4; ++r) {
                        float v = acc[mi][n][r] * alpha;
                        if (BIAS) v += bias[n0 + cb];
                        if (GELUF) v = gelu_exact(v);
                        ep[(wr * 16 + lk * 4 + r) * BN + cb] = __float2bfloat16(v);
                    }
                }
                __syncthreads();
#pragma unroll
                for (int i = 0; i < VE; ++i) {
                    int flat = (i * NT + tid) * 8;
                    int s = flat / EROW;
                    int rr = (flat % EROW) / BN;
                    int c = flat % BN;
                    long grow = m0 + s * FM * 16 + mi * 16 + rr;
                    *(short8*)((__hip_bfloat16*)Cp + Coff + grow * ldc + n0 + c) =
                        *(const short8*)(ep + flat);
                }
                __syncthreads();
            }
        } else {
            float* ep = (float*)smem;
            float* Cf = (float*)Cp;
            constexpr int VE = (WM * EROW) / (NT * 4);
#pragma unroll
            for (int mi = 0; mi < FM; ++mi) {
#pragma unroll
                for (int n = 0; n < FN; ++n) {
                    int cb = wc * FN * 16 + n * 16 + lr;
#pragma unroll
                    for (int r = 0; r < 4; ++r) {
                        float v = acc[mi][n][r] * alpha;
                        if (BIAS) v += bias[n0 + cb];
                        if (GELUF) v = gelu_exact(v);
                        ep[(wr * 16 + lk * 4 + r) * BN + cb] = v;
                    }
                }
                __syncthreads();
#pragma unroll
                for (int i = 0; i < VE; ++i) {
                    int flat = (i * NT + tid) * 4;
                    int s = flat / EROW;
                    int rr = (flat % EROW) / BN;
                    int c = flat % BN;
                    long grow = m0 + s * FM * 16 + mi * 16 + rr;
                    int gcol = n0 + c;
                    if (gcol + 4 <= Nc) {
                        *(float4*)(Cf + Coff + grow * ldc + gcol) =
                            *(const float4*)(ep + flat);
                    } else {
#pragma unroll
                        for (int e = 0; e < 4; ++e)
                            if (gcol + e < Nc)
                                Cf[Coff + grow * ldc + gcol + e] = ep[flat + e];
                    }
                }
                __syncthreads();
            }
        }
    } else {
#pragma unroll
        for (int m = 0; m < FM; ++m) {
            int rowb = m0 + wr * FM * 16 + m * 16 + lk * 4;
#pragma unroll
            for (int n = 0; n < FN; ++n) {
                int col = n0 + wc * FN * 16 + n * 16 + lr;
                if (col < Nc) {
#pragma unroll
                    for (int r = 0; r < 4; ++r) {
                        float v = acc[m][n][r] * alpha;
                        if (BIAS) v += bias[col];
                        if (GELUF) v = gelu_exact(v);
                        long cidx = Coff + (long)(rowb + r) * ldc + col;
                        float* Cf = (float*)Cp;
                        v += Cf[cidx];
                        Cf[cidx] = v;
                    }
                }
            }
        }
    }
}

// ---------------------------------------------------------------- merge per-row LSE partials -> nll
__global__ __launch_bounds__(256) void nll_part(const float2* __restrict__ part,
                                                const float* __restrict__ logits,
                                                const int* __restrict__ tgt,
                                                float* __restrict__ nll) {
    int row = blockIdx.x;
    const float2* p = part + (long)row * NPART;
    __shared__ float sm[4], ss[4];
    float m = -INFINITY, s = 0.f;
    for (int i = threadIdx.x; i < NPART; i += 256) {
        float2 v = p[i];
        float M = fmaxf(m, v.x);
        s = s * __expf(m - M) + v.y * __expf(v.x - M);
        m = M;
    }
    for (int o = 32; o; o >>= 1) {
        float om = __shfl_xor(m, o), os = __shfl_xor(s, o);
        float M = fmaxf(m, om);
        float e1 = (m == -INFINITY) ? 0.f : __expf(m - M);
        float e2 = (om == -INFINITY) ? 0.f : __expf(om - M);
        s = s * e1 + os * e2; m = M;
    }
    if ((threadIdx.x & 63) == 0) { sm[threadIdx.x >> 6] = m; ss[threadIdx.x >> 6] = s; }
    __syncthreads();
    if (threadIdx.x == 0) {
        float M = fmaxf(fmaxf(sm[0], sm[1]), fmaxf(sm[2], sm[3]));
        float S = ss[0] * expf(sm[0] - M) + ss[1] * expf(sm[1] - M) +
                  ss[2] * expf(sm[2] - M) + ss[3] * expf(sm[3] - M);
        nll[row] = M + logf(S) - logits[(long)row * NVOC + tgt[row]];
    }
}

__global__ __launch_bounds__(256) void loss_final(const float* __restrict__ nll,
                                                  float* __restrict__ out) {
    __shared__ float red[4];
    float s = 0.f;
    for (int i = threadIdx.x; i < NTOK; i += 256) s += nll[i];
    for (int o = 32; o; o >>= 1) s += __shfl_xor(s, o);
    if ((threadIdx.x & 63) == 0) red[threadIdx.x >> 6] = s;
    __syncthreads();
    if (threadIdx.x == 0)
        out[0] = (red[0] + red[1] + red[2] + red[3]) * (1.f / NTOK);
}

// ---------------------------------------------------------------- launch
extern "C" void kernel_launch(void* const* d_in, const int* in_sizes, int n_in,
                              void* d_out, int out_size, void* d_ws, size_t ws_size,
                              hipStream_t stream) {
    (void)in_sizes; (void)n_in; (void)out_size;
    const int*   idx  = (const int*)d_in[0];
    const int*   tgt  = (const int*)d_in[1];
    const float* tok  = (const float*)d_in[2];
    const float* pos  = (const float*)d_in[3];
    const float* ln1w = (const float*)d_in[4];
    const float* ln1b = (const float*)d_in[5];
    const float* attw = (const float*)d_in[6];
    const float* attb = (const float*)d_in[7];
    const float* prjw = (const float*)d_in[8];
    const float* prjb = (const float*)d_in[9];
    const float* ln2w = (const float*)d_in[10];
    const float* ln2b = (const float*)d_in[11];
    const float* fcw  = (const float*)d_in[12];
    const float* fcb  = (const float*)d_in[13];
    const float* fc2w = (const float*)d_in[14];
    const float* fc2b = (const float*)d_in[15];
    const float* lnfw = (const float*)d_in[16];
    const float* lnfb = (const float*)d_in[17];
    float* dof = (float*)d_out;

    char* base = (char*)d_ws;
    long off = 0;
    float* xf = (float*)(base + off);           off += (long)NTOK * DMODEL * 4;
    __hip_bfloat16* hbf  = (__hip_bfloat16*)(base + off); off += (long)NTOK * DMODEL * 2;
    __hip_bfloat16* qkvb = (__hip_bfloat16*)(base + off); off += (long)NTOK * 1536 * 2;
    __hip_bfloat16* Pb   = (__hip_bfloat16*)(base + off); off += 16L * TSEQ * TSEQ * 2;
    __hip_bfloat16* ybf  = (__hip_bfloat16*)(base + off); off += (long)NTOK * DMODEL * 2;
    __hip_bfloat16* fc1b = (__hip_bfloat16*)(base + off); off += (long)NTOK * 2048 * 2;
    __hip_bfloat16* wAtt = (__hip_bfloat16*)(base + off); off += 2L * 1536 * 512 * 2;
    __hip_bfloat16* wPrj = (__hip_bfloat16*)(base + off); off += 2L * 512 * 512 * 2;
    __hip_bfloat16* wFc  = (__hip_bfloat16*)(base + off); off += 2L * 2048 * 512 * 2;
    __hip_bfloat16* wFc2 = (__hip_bfloat16*)(base + off); off += 2L * 512 * 2048 * 2;
    __hip_bfloat16* tokB = (__hip_bfloat16*)(base + off); off += (long)VPAD * DMODEL * 2;
    float* nllb = (float*)(base + off);         off += NTOK * 4;
    float2* lseP = (float2*)Pb;   // aliases Pb (unused by fused attention path)
    if ((size_t)off > ws_size) return;

    conv_all<<<dim3(10240), 256, 0, stream>>>(attw, wAtt, prjw, wPrj,
                                              fcw, wFc, fc2w, wFc2, tok, tokB);

    embed_k<<<dim3(NTOK), 128, 0, stream>>>(idx, tok, pos, xf);

    for (int l = 0; l < 2; ++l) {
        ln_rows<<<dim3(512), 256, 0, stream>>>(xf, ln1w + l * 512, ln1b + l * 512, hbf, NTOK);
        gemm_bt<128, 64, 2, 2, true, true, false, false>
            <<<dim3(16, 24, 1), 256, 0, stream>>>(
            hbf, 512, 0, 0, wAtt + (long)l * 1536 * 512, 512, 0, 0,
            qkvb, 1536, 0, 0, attb + l * 1536, 512, 1536, 1.f, 1);
        attn_fused<<<dim3(16, 16), 256, 0, stream>>>(qkvb, ybf);
        gemm_bt<64, 64, 2, 2, false, true, false, true>
            <<<dim3(32, 8, 1), 256, 0, stream>>>(
            ybf, 512, 0, 0, wPrj + (long)l * 512 * 512, 512, 0, 0,
            xf, 512, 0, 0, prjb + l * 512, 512, 512, 1.f, 1);
        ln_rows<<<dim3(512), 256, 0, stream>>>(xf, ln2w + l * 512, ln2b + l * 512, hbf, NTOK);
        gemm_bt<128, 128, 2, 2, true, true, true, false>
            <<<dim3(16, 16, 1), 256, 0, stream>>>(
            hbf, 512, 0, 0, wFc + (long)l * 2048 * 512, 512, 0, 0,
            fc1b, 2048, 0, 0, fcb + l * 2048, 512, 2048, 1.f, 1);
        gemm_bt<64, 64, 2, 2, false, true, false, true>
            <<<dim3(32, 8, 1), 256, 0, stream>>>(
            fc1b, 2048, 0, 0, wFc2 + (long)l * 512 * 2048, 2048, 0, 0,
            xf, 512, 0, 0, fc2b + l * 512, 2048, 512, 1.f, 1);
    }

    ln_rows<<<dim3(512), 256, 0, stream>>>(xf, lnfw, lnfb, hbf, NTOK);
    // logits + fused partial-LSE: streaming head (786 blocks, chunked-XCD)
    head_stream<<<dim3(786), 512, 0, stream>>>(hbf, tokB, dof, lseP);

    nll_part<<<dim3(NTOK), 256, 0, stream>>>(lseP, dof, tgt, nllb);
    loss_final<<<dim3(1), 256, 0, stream>>>(nllb, dof + (long)NTOK * NVOC);
}